// Round 1
// baseline (366.351 us; speedup 1.0000x reference)
//
#include <hip/hip_runtime.h>

#define NNODES 10000
#define NHEADS 8
#define DHEAD 64
#define FEAT 512
#define NNETS 3
#define EDGES 160000
#define ETOT (NNETS * EDGES)

// ---------------- inv[n_id[i]] = i ----------------
__global__ __launch_bounds__(256) void build_inv_kernel(const int* __restrict__ n_id,
                                                        int* __restrict__ inv) {
    int i = blockIdx.x * 256 + threadIdx.x;
    if (i < NNODES) inv[n_id[i]] = i;
}

// ---------------- histogram of dst ----------------
__global__ __launch_bounds__(256) void hist_kernel(const int* __restrict__ edges,
                                                   const int* __restrict__ inv,
                                                   int* __restrict__ counts) {
    int eid = blockIdx.x * 256 + threadIdx.x;
    if (eid >= ETOT) return;
    int net = eid / EDGES;
    int e = eid - net * EDGES;
    int dstg = edges[net * (2 * EDGES) + EDGES + e];
    int dst = inv[dstg];
    atomicAdd(&counts[dst], 1);
}

// ---------------- exclusive scan of counts -> offsets[NNODES+1] ----------------
__global__ __launch_bounds__(1024) void scan_kernel(const int* __restrict__ counts,
                                                    int* __restrict__ offsets) {
    __shared__ int partial[1024];
    int t = threadIdx.x;
    const int PER = (NNODES + 1023) / 1024;  // 10
    int base = t * PER;
    int s = 0;
    for (int i = 0; i < PER; ++i) {
        int idx = base + i;
        if (idx < NNODES) s += counts[idx];
    }
    partial[t] = s;
    __syncthreads();
    for (int off = 1; off < 1024; off <<= 1) {
        int v = (t >= off) ? partial[t - off] : 0;
        __syncthreads();
        partial[t] += v;
        __syncthreads();
    }
    int running = (t == 0) ? 0 : partial[t - 1];
    for (int i = 0; i < PER; ++i) {
        int idx = base + i;
        if (idx < NNODES) {
            offsets[idx] = running;
            running += counts[idx];
        }
    }
    if (NNODES >= base && NNODES < base + PER) offsets[NNODES] = running;
}

// ---------------- scatter eids into dst-sorted order ----------------
__global__ __launch_bounds__(256) void scatter_kernel(const int* __restrict__ edges,
                                                      const int* __restrict__ inv,
                                                      const int* __restrict__ offsets,
                                                      int* __restrict__ cursor,
                                                      int* __restrict__ eid_sorted) {
    int eid = blockIdx.x * 256 + threadIdx.x;
    if (eid >= ETOT) return;
    int net = eid / EDGES;
    int e = eid - net * EDGES;
    int dstg = edges[net * (2 * EDGES) + EDGES + e];
    int dst = inv[dstg];
    int pos = atomicAdd(&cursor[dst], 1);
    eid_sorted[offsets[dst] + pos] = eid;
}

// ---------------- hfeat = x @ W  (f32, 64x64 tile, 4x4/thread) ----------------
#define BM 64
#define BN 64
#define BK 16
__global__ __launch_bounds__(256) void gemm_kernel(const float* __restrict__ A,
                                                   const float* __restrict__ B,
                                                   float* __restrict__ C, int M) {
    __shared__ float As[BK][BM];
    __shared__ float Bs[BK][BN];
    const int K = FEAT, N = FEAT;
    int t = threadIdx.x;
    int row0 = blockIdx.y * BM;
    int col0 = blockIdx.x * BN;
    int tx = t & 15, ty = t >> 4;
    float acc[4][4] = {};
    int am = t >> 2;          // 0..63
    int ak = (t & 3) * 4;     // 0..12
    int bk = t >> 4;          // 0..15
    int bn = (t & 15) * 4;    // 0..60
    for (int k0 = 0; k0 < K; k0 += BK) {
        float4 av;
        int arow = row0 + am;
        if (arow < M)
            av = *(const float4*)(&A[arow * K + k0 + ak]);
        else
            av = make_float4(0.f, 0.f, 0.f, 0.f);
        As[ak + 0][am] = av.x;
        As[ak + 1][am] = av.y;
        As[ak + 2][am] = av.z;
        As[ak + 3][am] = av.w;
        float4 bv = *(const float4*)(&B[(k0 + bk) * N + col0 + bn]);
        *(float4*)(&Bs[bk][bn]) = bv;
        __syncthreads();
#pragma unroll
        for (int kk = 0; kk < BK; ++kk) {
            float a[4], b[4];
#pragma unroll
            for (int i = 0; i < 4; ++i) a[i] = As[kk][ty * 4 + i];
#pragma unroll
            for (int j = 0; j < 4; ++j) b[j] = Bs[kk][tx * 4 + j];
#pragma unroll
            for (int i = 0; i < 4; ++i)
#pragma unroll
                for (int j = 0; j < 4; ++j) acc[i][j] += a[i] * b[j];
        }
        __syncthreads();
    }
#pragma unroll
    for (int i = 0; i < 4; ++i) {
        int r = row0 + ty * 4 + i;
        if (r < M) {
            float4 v = make_float4(acc[i][0], acc[i][1], acc[i][2], acc[i][3]);
            *(float4*)(&C[r * N + col0 + tx * 4]) = v;
        }
    }
}

// ---------------- per-node aggregation ----------------
__global__ __launch_bounds__(256) void aggregate_kernel(
    const int* __restrict__ eid_sorted, const int* __restrict__ offsets,
    const float* __restrict__ attns, const float* __restrict__ nw,
    const int* __restrict__ edges, const int* __restrict__ inv,
    const float* __restrict__ hfeat, const float* __restrict__ bias,
    float* __restrict__ out) {
    int n = blockIdx.x;
    int t = threadIdx.x;
    int c0 = t * 2;          // two consecutive columns per thread
    int h = c0 >> 6;         // head index (same for c0 and c0+1)
    int beg = offsets[n], end = offsets[n + 1];
    float acc0 = 0.f, acc1 = 0.f;
    for (int k = beg; k < end; ++k) {
        int eid = eid_sorted[k];
        int net = eid / EDGES;
        int e = eid - net * EDGES;
        float alpha = attns[eid * NHEADS + h] * nw[h * NNETS + net];
        int srcg = edges[net * (2 * EDGES) + e];
        int src = inv[srcg];
        float2 v = *(const float2*)(&hfeat[src * FEAT + c0]);
        acc0 += alpha * v.x;
        acc1 += alpha * v.y;
    }
    out[n * FEAT + c0] = acc0 + bias[c0];
    out[n * FEAT + c0 + 1] = acc1 + bias[c0 + 1];
}

extern "C" void kernel_launch(void* const* d_in, const int* in_sizes, int n_in,
                              void* d_out, int out_size, void* d_ws, size_t ws_size,
                              hipStream_t stream) {
    const float* x = (const float*)d_in[0];
    const int* n_id = (const int*)d_in[1];
    const float* attns = (const float*)d_in[2];
    const int* edges = (const int*)d_in[3];
    const float* nw = (const float*)d_in[4];
    const float* W = (const float*)d_in[5];
    const float* bias = (const float*)d_in[6];
    float* out = (float*)d_out;

    char* ws = (char*)d_ws;
    float* hfeat = (float*)(ws);                   // 20,480,000 B
    int* counts = (int*)(ws + 20480000);           // 40,000 B
    int* cursor = (int*)(ws + 20520000);           // 40,000 B
    int* offsets = (int*)(ws + 20560000);          // 40,016 B
    int* inv = (int*)(ws + 20600016);              // 40,000 B
    int* eids = (int*)(ws + 20640016);             // 1,920,000 B
    // total ~22.6 MB

    hipMemsetAsync(counts, 0, 80000, stream);  // counts + cursor (adjacent)
    build_inv_kernel<<<(NNODES + 255) / 256, 256, 0, stream>>>(n_id, inv);
    hist_kernel<<<(ETOT + 255) / 256, 256, 0, stream>>>(edges, inv, counts);
    scan_kernel<<<1, 1024, 0, stream>>>(counts, offsets);
    scatter_kernel<<<(ETOT + 255) / 256, 256, 0, stream>>>(edges, inv, offsets, cursor, eids);
    dim3 ggrid(FEAT / BN, (NNODES + BM - 1) / BM);
    gemm_kernel<<<ggrid, 256, 0, stream>>>(x, W, hfeat, NNODES);
    aggregate_kernel<<<NNODES, 256, 0, stream>>>(eids, offsets, attns, nw, edges, inv,
                                                 hfeat, bias, out);
}

// Round 2
// 251.729 us; speedup vs baseline: 1.4553x; 1.4553x over previous
//
#include <hip/hip_runtime.h>

#define NNODES 10000
#define NHEADS 8
#define DHEAD 64
#define FEAT 512
#define NNETS 3
#define EDGES 160000
#define ETOT (NNETS * EDGES)

typedef unsigned short ushort_t;

static __device__ __forceinline__ float b2f(ushort_t u) {
    return __uint_as_float(((unsigned)u) << 16);
}
static __device__ __forceinline__ ushort_t f2b(float f) {
    unsigned u = __float_as_uint(f);
    unsigned r = u + 0x7FFF + ((u >> 16) & 1);   // RNE
    return (ushort_t)(r >> 16);
}

// ---------------- inv[n_id[i]] = i ----------------
__global__ __launch_bounds__(256) void build_inv_kernel(const int* __restrict__ n_id,
                                                        int* __restrict__ inv) {
    int i = blockIdx.x * 256 + threadIdx.x;
    if (i < NNODES) inv[n_id[i]] = i;
}

// ---------------- histogram of dst ----------------
__global__ __launch_bounds__(256) void hist_kernel(const int* __restrict__ edges,
                                                   const int* __restrict__ inv,
                                                   int* __restrict__ counts) {
    int eid = blockIdx.x * 256 + threadIdx.x;
    if (eid >= ETOT) return;
    int net = eid / EDGES;
    int e = eid - net * EDGES;
    int dstg = edges[net * (2 * EDGES) + EDGES + e];
    int dst = inv[dstg];
    atomicAdd(&counts[dst], 1);
}

// ---------------- exclusive scan of counts -> offsets[NNODES+1] ----------------
__global__ __launch_bounds__(1024) void scan_kernel(const int* __restrict__ counts,
                                                    int* __restrict__ offsets) {
    __shared__ int partial[1024];
    int t = threadIdx.x;
    const int PER = (NNODES + 1023) / 1024;  // 10
    int base = t * PER;
    int s = 0;
    for (int i = 0; i < PER; ++i) {
        int idx = base + i;
        if (idx < NNODES) s += counts[idx];
    }
    partial[t] = s;
    __syncthreads();
    for (int off = 1; off < 1024; off <<= 1) {
        int v = (t >= off) ? partial[t - off] : 0;
        __syncthreads();
        partial[t] += v;
        __syncthreads();
    }
    int running = (t == 0) ? 0 : partial[t - 1];
    for (int i = 0; i < PER; ++i) {
        int idx = base + i;
        if (idx < NNODES) {
            offsets[idx] = running;
            running += counts[idx];
        }
    }
    if (NNODES >= base && NNODES < base + PER) offsets[NNODES] = running;
}

// ---------------- scatter eids into dst-sorted order ----------------
__global__ __launch_bounds__(256) void scatter_kernel(const int* __restrict__ edges,
                                                      const int* __restrict__ inv,
                                                      const int* __restrict__ offsets,
                                                      int* __restrict__ cursor,
                                                      int* __restrict__ eid_sorted) {
    int eid = blockIdx.x * 256 + threadIdx.x;
    if (eid >= ETOT) return;
    int net = eid / EDGES;
    int e = eid - net * EDGES;
    int dstg = edges[net * (2 * EDGES) + EDGES + e];
    int dst = inv[dstg];
    int pos = atomicAdd(&cursor[dst], 1);
    eid_sorted[offsets[dst] + pos] = eid;
}

// ---------------- prep: sorted src + per-head bf16 alpha streams ----------------
__global__ __launch_bounds__(256) void prep_kernel(const int* __restrict__ eids,
                                                   const int* __restrict__ edges,
                                                   const int* __restrict__ inv,
                                                   const float* __restrict__ attns,
                                                   const float* __restrict__ nw,
                                                   int* __restrict__ src_sorted,
                                                   ushort_t* __restrict__ alphab) {
    int k = blockIdx.x * 256 + threadIdx.x;
    if (k >= ETOT) return;
    int eid = eids[k];
    int net = eid / EDGES;
    int e = eid - net * EDGES;
    src_sorted[k] = inv[edges[net * (2 * EDGES) + e]];
#pragma unroll
    for (int h = 0; h < NHEADS; ++h) {
        float a = attns[(size_t)eid * NHEADS + h] * nw[h * NNETS + net];
        alphab[(size_t)h * ETOT + k] = f2b(a);
    }
}

// ---------------- hfeat = x @ W  (f32 compute, bf16 output) ----------------
#define BM 64
#define BN 64
#define BK 16
__global__ __launch_bounds__(256) void gemm_kernel(const float* __restrict__ A,
                                                   const float* __restrict__ B,
                                                   ushort_t* __restrict__ Cb, int M) {
    __shared__ float As[BK][BM];
    __shared__ float Bs[BK][BN];
    const int K = FEAT, N = FEAT;
    int t = threadIdx.x;
    int row0 = blockIdx.y * BM;
    int col0 = blockIdx.x * BN;
    int tx = t & 15, ty = t >> 4;
    float acc[4][4] = {};
    int am = t >> 2;          // 0..63
    int ak = (t & 3) * 4;     // 0..12
    int bk = t >> 4;          // 0..15
    int bn = (t & 15) * 4;    // 0..60
    for (int k0 = 0; k0 < K; k0 += BK) {
        float4 av;
        int arow = row0 + am;
        if (arow < M)
            av = *(const float4*)(&A[arow * K + k0 + ak]);
        else
            av = make_float4(0.f, 0.f, 0.f, 0.f);
        As[ak + 0][am] = av.x;
        As[ak + 1][am] = av.y;
        As[ak + 2][am] = av.z;
        As[ak + 3][am] = av.w;
        float4 bv = *(const float4*)(&B[(k0 + bk) * N + col0 + bn]);
        *(float4*)(&Bs[bk][bn]) = bv;
        __syncthreads();
#pragma unroll
        for (int kk = 0; kk < BK; ++kk) {
            float a[4], b[4];
#pragma unroll
            for (int i = 0; i < 4; ++i) a[i] = As[kk][ty * 4 + i];
#pragma unroll
            for (int j = 0; j < 4; ++j) b[j] = Bs[kk][tx * 4 + j];
#pragma unroll
            for (int i = 0; i < 4; ++i)
#pragma unroll
                for (int j = 0; j < 4; ++j) acc[i][j] += a[i] * b[j];
        }
        __syncthreads();
    }
#pragma unroll
    for (int i = 0; i < 4; ++i) {
        int r = row0 + ty * 4 + i;
        if (r < M) {
            ushort4 v;
            v.x = f2b(acc[i][0]);
            v.y = f2b(acc[i][1]);
            v.z = f2b(acc[i][2]);
            v.w = f2b(acc[i][3]);
            *(ushort4*)(&Cb[(size_t)r * N + col0 + tx * 4]) = v;
        }
    }
}

// ---------------- per-(node, head) aggregation: out_h = A_h @ hfeat_h ----------------
__global__ __launch_bounds__(64) void aggregate_kernel(
    const int* __restrict__ src_sorted, const int* __restrict__ offsets,
    const ushort_t* __restrict__ alphab, const ushort_t* __restrict__ hfeatb,
    const float* __restrict__ bias, float* __restrict__ out) {
    int n = blockIdx.x;
    int h = blockIdx.y;
    int t = threadIdx.x;
    int beg = offsets[n], end = offsets[n + 1];
    const ushort_t* ah = alphab + (size_t)h * ETOT;
    const ushort_t* hb = hfeatb + h * DHEAD + t;
    float acc = 0.f;
    int k = beg;
    for (; k + 3 < end; k += 4) {
        int s0 = src_sorted[k + 0];
        int s1 = src_sorted[k + 1];
        int s2 = src_sorted[k + 2];
        int s3 = src_sorted[k + 3];
        float a0 = b2f(ah[k + 0]);
        float a1 = b2f(ah[k + 1]);
        float a2 = b2f(ah[k + 2]);
        float a3 = b2f(ah[k + 3]);
        float v0 = b2f(hb[(size_t)s0 * FEAT]);
        float v1 = b2f(hb[(size_t)s1 * FEAT]);
        float v2 = b2f(hb[(size_t)s2 * FEAT]);
        float v3 = b2f(hb[(size_t)s3 * FEAT]);
        acc += a0 * v0;
        acc += a1 * v1;
        acc += a2 * v2;
        acc += a3 * v3;
    }
    for (; k < end; ++k) {
        int s = src_sorted[k];
        acc += b2f(ah[k]) * b2f(hb[(size_t)s * FEAT]);
    }
    int c = h * DHEAD + t;
    out[(size_t)n * FEAT + c] = acc + bias[c];
}

extern "C" void kernel_launch(void* const* d_in, const int* in_sizes, int n_in,
                              void* d_out, int out_size, void* d_ws, size_t ws_size,
                              hipStream_t stream) {
    const float* x = (const float*)d_in[0];
    const int* n_id = (const int*)d_in[1];
    const float* attns = (const float*)d_in[2];
    const int* edges = (const int*)d_in[3];
    const float* nw = (const float*)d_in[4];
    const float* W = (const float*)d_in[5];
    const float* bias = (const float*)d_in[6];
    float* out = (float*)d_out;

    char* ws = (char*)d_ws;
    ushort_t* hfeatb = (ushort_t*)(ws);                  // 10,240,000 B
    ushort_t* alphab = (ushort_t*)(ws + 10240000);       //  7,680,000 B
    int* src_sorted = (int*)(ws + 17920000);             //  1,920,000 B
    int* eids = (int*)(ws + 19840000);                   //  1,920,000 B
    int* counts = (int*)(ws + 21760000);                 //     40,000 B
    int* cursor = (int*)(ws + 21800000);                 //     40,000 B
    int* offsets = (int*)(ws + 21840000);                //     40,004 B
    int* inv = (int*)(ws + 21880004);                    //     40,000 B
    // total ~21.92 MB

    hipMemsetAsync(counts, 0, 80000, stream);  // counts + cursor (adjacent)
    build_inv_kernel<<<(NNODES + 255) / 256, 256, 0, stream>>>(n_id, inv);
    hist_kernel<<<(ETOT + 255) / 256, 256, 0, stream>>>(edges, inv, counts);
    scan_kernel<<<1, 1024, 0, stream>>>(counts, offsets);
    scatter_kernel<<<(ETOT + 255) / 256, 256, 0, stream>>>(edges, inv, offsets, cursor, eids);
    prep_kernel<<<(ETOT + 255) / 256, 256, 0, stream>>>(eids, edges, inv, attns, nw,
                                                        src_sorted, alphab);
    dim3 ggrid(FEAT / BN, (NNODES + BM - 1) / BM);
    gemm_kernel<<<ggrid, 256, 0, stream>>>(x, W, hfeatb, NNODES);
    dim3 agrid(NNODES, NHEADS);
    aggregate_kernel<<<agrid, 64, 0, stream>>>(src_sorted, offsets, alphab, hfeatb,
                                               bias, out);
}

// Round 3
// 198.629 us; speedup vs baseline: 1.8444x; 1.2673x over previous
//
#include <hip/hip_runtime.h>

#define NNODES 10000
#define NHEADS 8
#define DHEAD 64
#define FEAT 512
#define NNETS 3
#define EDGES 160000
#define ETOT (NNETS * EDGES)

typedef unsigned short ushort_t;
typedef __bf16 bf16x8 __attribute__((ext_vector_type(8)));
typedef float f32x4 __attribute__((ext_vector_type(4)));

static __device__ __forceinline__ float b2f(ushort_t u) {
    return __uint_as_float(((unsigned)u) << 16);
}
static __device__ __forceinline__ ushort_t f2b(float f) {
    unsigned u = __float_as_uint(f);
    unsigned r = u + 0x7FFF + ((u >> 16) & 1);   // RNE
    return (ushort_t)(r >> 16);
}

static __device__ __forceinline__ void mfma16(f32x4& d, bf16x8 a, bf16x8 b) {
    asm volatile("v_mfma_f32_16x16x32_bf16 %0, %1, %2, %0" : "+v"(d) : "v"(a), "v"(b));
}

#define GLDS(gp, lp)                                                                     \
    __builtin_amdgcn_global_load_lds((const __attribute__((address_space(1))) void*)(gp), \
                                     (__attribute__((address_space(3))) void*)(lp), 16, 0, 0)

// ---------------- inv[n_id[i]] = i ----------------
__global__ __launch_bounds__(256) void build_inv_kernel(const int* __restrict__ n_id,
                                                        int* __restrict__ inv) {
    int i = blockIdx.x * 256 + threadIdx.x;
    if (i < NNODES) inv[n_id[i]] = i;
}

// ---------------- histogram of dst ----------------
__global__ __launch_bounds__(256) void hist_kernel(const int* __restrict__ edges,
                                                   const int* __restrict__ inv,
                                                   int* __restrict__ counts) {
    int eid = blockIdx.x * 256 + threadIdx.x;
    if (eid >= ETOT) return;
    int net = eid / EDGES;
    int e = eid - net * EDGES;
    int dstg = edges[net * (2 * EDGES) + EDGES + e];
    int dst = inv[dstg];
    atomicAdd(&counts[dst], 1);
}

// ---------------- exclusive scan of counts -> offsets[NNODES+1] ----------------
__global__ __launch_bounds__(1024) void scan_kernel(const int* __restrict__ counts,
                                                    int* __restrict__ offsets) {
    __shared__ int partial[1024];
    int t = threadIdx.x;
    const int PER = (NNODES + 1023) / 1024;  // 10
    int base = t * PER;
    int s = 0;
    for (int i = 0; i < PER; ++i) {
        int idx = base + i;
        if (idx < NNODES) s += counts[idx];
    }
    partial[t] = s;
    __syncthreads();
    for (int off = 1; off < 1024; off <<= 1) {
        int v = (t >= off) ? partial[t - off] : 0;
        __syncthreads();
        partial[t] += v;
        __syncthreads();
    }
    int running = (t == 0) ? 0 : partial[t - 1];
    for (int i = 0; i < PER; ++i) {
        int idx = base + i;
        if (idx < NNODES) {
            offsets[idx] = running;
            running += counts[idx];
        }
    }
    if (NNODES >= base && NNODES < base + PER) offsets[NNODES] = running;
}

// ---------------- scatter eids into dst-sorted order ----------------
__global__ __launch_bounds__(256) void scatter_kernel(const int* __restrict__ edges,
                                                      const int* __restrict__ inv,
                                                      const int* __restrict__ offsets,
                                                      int* __restrict__ cursor,
                                                      int* __restrict__ eid_sorted) {
    int eid = blockIdx.x * 256 + threadIdx.x;
    if (eid >= ETOT) return;
    int net = eid / EDGES;
    int e = eid - net * EDGES;
    int dstg = edges[net * (2 * EDGES) + EDGES + e];
    int dst = inv[dstg];
    int pos = atomicAdd(&cursor[dst], 1);
    eid_sorted[offsets[dst] + pos] = eid;
}

// ---------------- prep: sorted src + per-head bf16 alpha streams ----------------
__global__ __launch_bounds__(256) void prep_kernel(const int* __restrict__ eids,
                                                   const int* __restrict__ edges,
                                                   const int* __restrict__ inv,
                                                   const float* __restrict__ attns,
                                                   const float* __restrict__ nw,
                                                   int* __restrict__ src_sorted,
                                                   ushort_t* __restrict__ alphab) {
    int k = blockIdx.x * 256 + threadIdx.x;
    if (k >= ETOT) return;
    int eid = eids[k];
    int net = eid / EDGES;
    int e = eid - net * EDGES;
    src_sorted[k] = inv[edges[net * (2 * EDGES) + e]];
#pragma unroll
    for (int h = 0; h < NHEADS; ++h) {
        float a = attns[(size_t)eid * NHEADS + h] * nw[h * NNETS + net];
        alphab[(size_t)h * ETOT + k] = f2b(a);
    }
}

// ---------------- x (f32) -> xb (bf16) ----------------
__global__ __launch_bounds__(256) void cvt_x_kernel(const float* __restrict__ x,
                                                    ushort_t* __restrict__ xb) {
    int i = (blockIdx.x * 256 + threadIdx.x) * 4;
    if (i < NNODES * FEAT) {
        float4 v = *(const float4*)(x + i);
        ushort4 o;
        o.x = f2b(v.x);
        o.y = f2b(v.y);
        o.z = f2b(v.z);
        o.w = f2b(v.w);
        *(ushort4*)(xb + i) = o;
    }
}

// ---------------- W (f32, KxN) -> wbt (bf16, NxK transposed) ----------------
__global__ __launch_bounds__(256) void cvt_wt_kernel(const float* __restrict__ W,
                                                     ushort_t* __restrict__ wbt) {
    __shared__ float tile[32][33];
    int k0 = blockIdx.y * 32, n0 = blockIdx.x * 32;
    int t = threadIdx.x;
    int r = t >> 3, c4 = (t & 7) * 4;
    float4 v = *(const float4*)(&W[(size_t)(k0 + r) * FEAT + n0 + c4]);
    tile[r][c4 + 0] = v.x;
    tile[r][c4 + 1] = v.y;
    tile[r][c4 + 2] = v.z;
    tile[r][c4 + 3] = v.w;
    __syncthreads();
    ushort4 o;
    o.x = f2b(tile[c4 + 0][r]);
    o.y = f2b(tile[c4 + 1][r]);
    o.z = f2b(tile[c4 + 2][r]);
    o.w = f2b(tile[c4 + 3][r]);
    *(ushort4*)(&wbt[(size_t)(n0 + r) * FEAT + k0 + c4]) = o;
}

// ---------------- hfeat = xb @ wbt^T  (bf16 MFMA, 128x128 tile, 4 waves) ----------------
__global__ __launch_bounds__(256) void gemm_mfma_kernel(const ushort_t* __restrict__ xb,
                                                        const ushort_t* __restrict__ wbt,
                                                        ushort_t* __restrict__ Cb) {
    __shared__ ushort_t Alds[128 * 32];
    __shared__ ushort_t Blds[128 * 32];
    const int t = threadIdx.x;
    const int wv = t >> 6;
    const int l = t & 63;
    const int lane15 = l & 15;
    const int hi = l >> 4;
    const int r0 = blockIdx.y * 128;
    const int c0 = blockIdx.x * 128;
    const int WR = (wv >> 1) * 64;
    const int WC = (wv & 1) * 64;

    // staging: issue i covers rows i*64..i*64+63; wave wv rows wv*16+(l>>2); col (l&3)*8
    const int srow = (wv << 4) + (l >> 2);
    const int scol = (l & 3) << 3;
    const ushort_t* Ab0 = xb + (size_t)min(r0 + srow, NNODES - 1) * FEAT + scol;
    const ushort_t* Ab1 = xb + (size_t)min(r0 + 64 + srow, NNODES - 1) * FEAT + scol;
    const ushort_t* Bb0 = wbt + (size_t)(c0 + srow) * FEAT + scol;
    const ushort_t* Bb1 = wbt + (size_t)(c0 + 64 + srow) * FEAT + scol;
    ushort_t* Al0 = &Alds[wv * 512];        // wave-uniform LDS bases (lane*16B implicit)
    ushort_t* Al1 = &Alds[2048 + wv * 512];
    ushort_t* Bl0 = &Blds[wv * 512];
    ushort_t* Bl1 = &Blds[2048 + wv * 512];

    f32x4 acc[4][4] = {};

    for (int k0 = 0; k0 < FEAT; k0 += 32) {
        GLDS(Ab0 + k0, Al0);
        GLDS(Ab1 + k0, Al1);
        GLDS(Bb0 + k0, Bl0);
        GLDS(Bb1 + k0, Bl1);
        __syncthreads();  // compiler drains vmcnt before s_barrier
        bf16x8 a[4], b[4];
        const ushort_t* Ap = &Alds[(WR + lane15) * 32 + hi * 8];
        const ushort_t* Bp = &Blds[(WC + lane15) * 32 + hi * 8];
#pragma unroll
        for (int m = 0; m < 4; ++m) a[m] = *(const bf16x8*)(Ap + m * 512);
#pragma unroll
        for (int n = 0; n < 4; ++n) b[n] = *(const bf16x8*)(Bp + n * 512);
#pragma unroll
        for (int m = 0; m < 4; ++m)
#pragma unroll
            for (int n = 0; n < 4; ++n) mfma16(acc[m][n], a[m], b[n]);
        __syncthreads();
    }
    asm volatile("s_nop 7\n\ts_nop 7\n\ts_nop 7" ::);  // MFMA->VALU hazard guard
#pragma unroll
    for (int m = 0; m < 4; ++m) {
#pragma unroll
        for (int rr = 0; rr < 4; ++rr) {
            int row = r0 + WR + m * 16 + hi * 4 + rr;
            if (row < NNODES) {
#pragma unroll
                for (int n = 0; n < 4; ++n) {
                    int col = c0 + WC + n * 16 + lane15;
                    Cb[(size_t)row * FEAT + col] = f2b(acc[m][n][rr]);
                }
            }
        }
    }
}

// ---------------- per-(node, head) aggregation: out_h = A_h @ hfeat_h ----------------
__global__ __launch_bounds__(64) void aggregate_kernel(
    const int* __restrict__ src_sorted, const int* __restrict__ offsets,
    const ushort_t* __restrict__ alphab, const ushort_t* __restrict__ hfeatb,
    const float* __restrict__ bias, float* __restrict__ out) {
    int n = blockIdx.x;
    int h = blockIdx.y;
    int t = threadIdx.x;
    int beg = offsets[n], end = offsets[n + 1];
    const ushort_t* ah = alphab + (size_t)h * ETOT;
    const ushort_t* hb = hfeatb + h * DHEAD + t;
    float acc = 0.f;
    int k = beg;
    for (; k + 3 < end; k += 4) {
        int s0 = src_sorted[k + 0];
        int s1 = src_sorted[k + 1];
        int s2 = src_sorted[k + 2];
        int s3 = src_sorted[k + 3];
        float a0 = b2f(ah[k + 0]);
        float a1 = b2f(ah[k + 1]);
        float a2 = b2f(ah[k + 2]);
        float a3 = b2f(ah[k + 3]);
        float v0 = b2f(hb[(size_t)s0 * FEAT]);
        float v1 = b2f(hb[(size_t)s1 * FEAT]);
        float v2 = b2f(hb[(size_t)s2 * FEAT]);
        float v3 = b2f(hb[(size_t)s3 * FEAT]);
        acc += a0 * v0;
        acc += a1 * v1;
        acc += a2 * v2;
        acc += a3 * v3;
    }
    for (; k < end; ++k) {
        int s = src_sorted[k];
        acc += b2f(ah[k]) * b2f(hb[(size_t)s * FEAT]);
    }
    int c = h * DHEAD + t;
    out[(size_t)n * FEAT + c] = acc + bias[c];
}

extern "C" void kernel_launch(void* const* d_in, const int* in_sizes, int n_in,
                              void* d_out, int out_size, void* d_ws, size_t ws_size,
                              hipStream_t stream) {
    const float* x = (const float*)d_in[0];
    const int* n_id = (const int*)d_in[1];
    const float* attns = (const float*)d_in[2];
    const int* edges = (const int*)d_in[3];
    const float* nw = (const float*)d_in[4];
    const float* W = (const float*)d_in[5];
    const float* bias = (const float*)d_in[6];
    float* out = (float*)d_out;

    char* ws = (char*)d_ws;
    size_t o = 0;
    ushort_t* hfeatb = (ushort_t*)(ws + o); o += 10240000;
    ushort_t* alphab = (ushort_t*)(ws + o); o += 7680000;
    ushort_t* xb     = (ushort_t*)(ws + o); o += 10240000;
    ushort_t* wbt    = (ushort_t*)(ws + o); o += 524288;
    int* src_sorted  = (int*)(ws + o);      o += 1920000;
    int* eids        = (int*)(ws + o);      o += 1920000;
    int* counts      = (int*)(ws + o);      o += 40000;
    int* cursor      = (int*)(ws + o);      o += 40000;
    int* offsets     = (int*)(ws + o);      o += 40016;
    int* inv         = (int*)(ws + o);      o += 40000;
    // total ~32.7 MB

    hipMemsetAsync(counts, 0, 80000, stream);  // counts + cursor (adjacent)
    build_inv_kernel<<<(NNODES + 255) / 256, 256, 0, stream>>>(n_id, inv);
    hist_kernel<<<(ETOT + 255) / 256, 256, 0, stream>>>(edges, inv, counts);
    scan_kernel<<<1, 1024, 0, stream>>>(counts, offsets);
    scatter_kernel<<<(ETOT + 255) / 256, 256, 0, stream>>>(edges, inv, offsets, cursor, eids);
    prep_kernel<<<(ETOT + 255) / 256, 256, 0, stream>>>(eids, edges, inv, attns, nw,
                                                        src_sorted, alphab);
    cvt_x_kernel<<<(NNODES * FEAT / 4 + 255) / 256, 256, 0, stream>>>(x, xb);
    dim3 wgrid(FEAT / 32, FEAT / 32);
    cvt_wt_kernel<<<wgrid, 256, 0, stream>>>(W, wbt);
    dim3 ggrid(FEAT / 128, (NNODES + 127) / 128);
    gemm_mfma_kernel<<<ggrid, 256, 0, stream>>>(xb, wbt, hfeatb);
    dim3 agrid(NNODES, NHEADS);
    aggregate_kernel<<<agrid, 64, 0, stream>>>(src_sorted, offsets, alphab, hfeatb,
                                               bias, out);
}

// Round 4
// 178.225 us; speedup vs baseline: 2.0556x; 1.1145x over previous
//
#include <hip/hip_runtime.h>

#define NNODES 10000
#define NHEADS 8
#define DHEAD 64
#define FEAT 512
#define NNETS 3
#define EDGES 160000
#define ETOT (NNETS * EDGES)

typedef unsigned short ushort_t;
typedef __bf16 bf16x8 __attribute__((ext_vector_type(8)));
typedef float f32x4 __attribute__((ext_vector_type(4)));

static __device__ __forceinline__ float b2f(ushort_t u) {
    return __uint_as_float(((unsigned)u) << 16);
}
static __device__ __forceinline__ ushort_t f2b(float f) {
    unsigned u = __float_as_uint(f);
    unsigned r = u + 0x7FFF + ((u >> 16) & 1);   // RNE
    return (ushort_t)(r >> 16);
}

static __device__ __forceinline__ void mfma16(f32x4& d, bf16x8 a, bf16x8 b) {
    asm volatile("v_mfma_f32_16x16x32_bf16 %0, %1, %2, %0" : "+v"(d) : "v"(a), "v"(b));
}

#define GLDS(gp, lp)                                                                     \
    __builtin_amdgcn_global_load_lds((const __attribute__((address_space(1))) void*)(gp), \
                                     (__attribute__((address_space(3))) void*)(lp), 16, 0, 0)

// ---------------- inv[n_id[i]] = i ----------------
__global__ __launch_bounds__(256) void build_inv_kernel(const int* __restrict__ n_id,
                                                        int* __restrict__ inv) {
    int i = blockIdx.x * 256 + threadIdx.x;
    if (i < NNODES) inv[n_id[i]] = i;
}

// ---------------- histogram of dst ----------------
__global__ __launch_bounds__(256) void hist_kernel(const int* __restrict__ edges,
                                                   const int* __restrict__ inv,
                                                   int* __restrict__ counts) {
    int eid = blockIdx.x * 256 + threadIdx.x;
    if (eid >= ETOT) return;
    int net = eid / EDGES;
    int e = eid - net * EDGES;
    int dstg = edges[net * (2 * EDGES) + EDGES + e];
    int dst = inv[dstg];
    atomicAdd(&counts[dst], 1);
}

// ---------------- exclusive scan of counts -> offsets[NNODES+1] ----------------
__global__ __launch_bounds__(1024) void scan_kernel(const int* __restrict__ counts,
                                                    int* __restrict__ offsets) {
    __shared__ int partial[1024];
    int t = threadIdx.x;
    const int PER = (NNODES + 1023) / 1024;  // 10
    int base = t * PER;
    int s = 0;
    for (int i = 0; i < PER; ++i) {
        int idx = base + i;
        if (idx < NNODES) s += counts[idx];
    }
    partial[t] = s;
    __syncthreads();
    for (int off = 1; off < 1024; off <<= 1) {
        int v = (t >= off) ? partial[t - off] : 0;
        __syncthreads();
        partial[t] += v;
        __syncthreads();
    }
    int running = (t == 0) ? 0 : partial[t - 1];
    for (int i = 0; i < PER; ++i) {
        int idx = base + i;
        if (idx < NNODES) {
            offsets[idx] = running;
            running += counts[idx];
        }
    }
    if (NNODES >= base && NNODES < base + PER) offsets[NNODES] = running;
}

// ---------------- scatter + alpha-prep fused: dst-sorted src + [Etot][8] bf16 alpha ----
__global__ __launch_bounds__(256) void scatter_kernel(const int* __restrict__ edges,
                                                      const int* __restrict__ inv,
                                                      const int* __restrict__ offsets,
                                                      int* __restrict__ cursor,
                                                      const float* __restrict__ attns,
                                                      const float* __restrict__ nw,
                                                      int* __restrict__ src_sorted,
                                                      ushort_t* __restrict__ alphab) {
    int eid = blockIdx.x * 256 + threadIdx.x;
    if (eid >= ETOT) return;
    int net = eid / EDGES;
    int e = eid - net * EDGES;
    int srcg = edges[net * (2 * EDGES) + e];
    int dstg = edges[net * (2 * EDGES) + EDGES + e];
    int dst = inv[dstg];
    int pos = offsets[dst] + atomicAdd(&cursor[dst], 1);
    src_sorted[pos] = inv[srcg];
    // coalesced 32B read of this edge's 8 head attns
    float4 A0 = *(const float4*)(&attns[(size_t)eid * NHEADS]);
    float4 A1 = *(const float4*)(&attns[(size_t)eid * NHEADS + 4]);
    ushort4 o0, o1;
    o0.x = f2b(A0.x * nw[0 * NNETS + net]);
    o0.y = f2b(A0.y * nw[1 * NNETS + net]);
    o0.z = f2b(A0.z * nw[2 * NNETS + net]);
    o0.w = f2b(A0.w * nw[3 * NNETS + net]);
    o1.x = f2b(A1.x * nw[4 * NNETS + net]);
    o1.y = f2b(A1.y * nw[5 * NNETS + net]);
    o1.z = f2b(A1.z * nw[6 * NNETS + net]);
    o1.w = f2b(A1.w * nw[7 * NNETS + net]);
    *(ushort4*)(&alphab[(size_t)pos * NHEADS]) = o0;
    *(ushort4*)(&alphab[(size_t)pos * NHEADS + 4]) = o1;
}

// ---------------- x (f32) -> xb (bf16) ----------------
__global__ __launch_bounds__(256) void cvt_x_kernel(const float* __restrict__ x,
                                                    ushort_t* __restrict__ xb) {
    int i = (blockIdx.x * 256 + threadIdx.x) * 4;
    if (i < NNODES * FEAT) {
        float4 v = *(const float4*)(x + i);
        ushort4 o;
        o.x = f2b(v.x);
        o.y = f2b(v.y);
        o.z = f2b(v.z);
        o.w = f2b(v.w);
        *(ushort4*)(xb + i) = o;
    }
}

// ---------------- W (f32, KxN) -> wbt (bf16, NxK transposed) ----------------
__global__ __launch_bounds__(256) void cvt_wt_kernel(const float* __restrict__ W,
                                                     ushort_t* __restrict__ wbt) {
    __shared__ float tile[32][33];
    int k0 = blockIdx.y * 32, n0 = blockIdx.x * 32;
    int t = threadIdx.x;
    int r = t >> 3, c4 = (t & 7) * 4;
    float4 v = *(const float4*)(&W[(size_t)(k0 + r) * FEAT + n0 + c4]);
    tile[r][c4 + 0] = v.x;
    tile[r][c4 + 1] = v.y;
    tile[r][c4 + 2] = v.z;
    tile[r][c4 + 3] = v.w;
    __syncthreads();
    ushort4 o;
    o.x = f2b(tile[c4 + 0][r]);
    o.y = f2b(tile[c4 + 1][r]);
    o.z = f2b(tile[c4 + 2][r]);
    o.w = f2b(tile[c4 + 3][r]);
    *(ushort4*)(&wbt[(size_t)(n0 + r) * FEAT + k0 + c4]) = o;
}

// ---- hfeat = xb @ wbt^T (bf16 MFMA, 128x128 tile), epilogue writes [N][D][H] ----
__global__ __launch_bounds__(256) void gemm_mfma_kernel(const ushort_t* __restrict__ xb,
                                                        const ushort_t* __restrict__ wbt,
                                                        ushort_t* __restrict__ Cq) {
    __shared__ ushort_t Alds[128 * 32];
    __shared__ ushort_t Blds[128 * 32];
    const int t = threadIdx.x;
    const int wv = t >> 6;
    const int l = t & 63;
    const int lane15 = l & 15;
    const int hi = l >> 4;
    const int r0 = blockIdx.y * 128;
    const int c0 = blockIdx.x * 128;
    const int WR = (wv >> 1) * 64;
    const int WC = (wv & 1) * 64;

    const int srow = (wv << 4) + (l >> 2);
    const int scol = (l & 3) << 3;
    const ushort_t* Ab0 = xb + (size_t)min(r0 + srow, NNODES - 1) * FEAT + scol;
    const ushort_t* Ab1 = xb + (size_t)min(r0 + 64 + srow, NNODES - 1) * FEAT + scol;
    const ushort_t* Bb0 = wbt + (size_t)(c0 + srow) * FEAT + scol;
    const ushort_t* Bb1 = wbt + (size_t)(c0 + 64 + srow) * FEAT + scol;
    ushort_t* Al0 = &Alds[wv * 512];
    ushort_t* Al1 = &Alds[2048 + wv * 512];
    ushort_t* Bl0 = &Blds[wv * 512];
    ushort_t* Bl1 = &Blds[2048 + wv * 512];

    f32x4 acc[4][4] = {};

    for (int k0 = 0; k0 < FEAT; k0 += 32) {
        GLDS(Ab0 + k0, Al0);
        GLDS(Ab1 + k0, Al1);
        GLDS(Bb0 + k0, Bl0);
        GLDS(Bb1 + k0, Bl1);
        __syncthreads();
        bf16x8 a[4], b[4];
        const ushort_t* Ap = &Alds[(WR + lane15) * 32 + hi * 8];
        const ushort_t* Bp = &Blds[(WC + lane15) * 32 + hi * 8];
#pragma unroll
        for (int m = 0; m < 4; ++m) a[m] = *(const bf16x8*)(Ap + m * 512);
#pragma unroll
        for (int n = 0; n < 4; ++n) b[n] = *(const bf16x8*)(Bp + n * 512);
#pragma unroll
        for (int m = 0; m < 4; ++m)
#pragma unroll
            for (int n = 0; n < 4; ++n) mfma16(acc[m][n], a[m], b[n]);
        __syncthreads();
    }
    asm volatile("s_nop 7\n\ts_nop 7\n\ts_nop 7" ::);  // MFMA->VALU hazard guard
    const int h = (c0 + WC) >> 6;  // head: fixed per wave (64-col span)
#pragma unroll
    for (int m = 0; m < 4; ++m) {
#pragma unroll
        for (int rr = 0; rr < 4; ++rr) {
            int row = r0 + WR + m * 16 + hi * 4 + rr;
            if (row < NNODES) {
#pragma unroll
                for (int n = 0; n < 4; ++n) {
                    int d = n * 16 + lane15;  // 0..63 within head
                    Cq[(size_t)row * FEAT + d * NHEADS + h] = f2b(acc[m][n][rr]);
                }
            }
        }
    }
}

// ---- aggregation: 4 waves/block, 1 node/wave, lane=column d, all 8 heads at once ----
static __device__ __forceinline__ void fma_pair(unsigned a, unsigned h, float& lo,
                                                float& hi) {
    float alo = __uint_as_float(a << 16);
    float ahi = __uint_as_float(a & 0xFFFF0000u);
    float hlo = __uint_as_float(h << 16);
    float hhi = __uint_as_float(h & 0xFFFF0000u);
    lo = fmaf(alo, hlo, lo);
    hi = fmaf(ahi, hhi, hi);
}

__global__ __launch_bounds__(256) void aggregate_kernel(
    const int* __restrict__ src_sorted, const int* __restrict__ offsets,
    const ushort_t* __restrict__ alphab, const ushort_t* __restrict__ hfeatq,
    const float* __restrict__ bias, float* __restrict__ out) {
    int wv = threadIdx.x >> 6;
    int t = threadIdx.x & 63;  // column d
    int n = blockIdx.x * 4 + wv;
    if (n >= NNODES) return;
    int beg = offsets[n], end = offsets[n + 1];
    float acc[8] = {};
    const ushort_t* hp = hfeatq + t * NHEADS;
    int k = beg;
    for (; k + 1 < end; k += 2) {
        int s0 = src_sorted[k];
        int s1 = src_sorted[k + 1];
        uint4 al0 = *(const uint4*)(&alphab[(size_t)k * NHEADS]);
        uint4 al1 = *(const uint4*)(&alphab[(size_t)(k + 1) * NHEADS]);
        uint4 h0 = *(const uint4*)(hp + (size_t)s0 * FEAT);
        uint4 h1 = *(const uint4*)(hp + (size_t)s1 * FEAT);
        fma_pair(al0.x, h0.x, acc[0], acc[1]);
        fma_pair(al0.y, h0.y, acc[2], acc[3]);
        fma_pair(al0.z, h0.z, acc[4], acc[5]);
        fma_pair(al0.w, h0.w, acc[6], acc[7]);
        fma_pair(al1.x, h1.x, acc[0], acc[1]);
        fma_pair(al1.y, h1.y, acc[2], acc[3]);
        fma_pair(al1.z, h1.z, acc[4], acc[5]);
        fma_pair(al1.w, h1.w, acc[6], acc[7]);
    }
    if (k < end) {
        int s0 = src_sorted[k];
        uint4 al0 = *(const uint4*)(&alphab[(size_t)k * NHEADS]);
        uint4 h0 = *(const uint4*)(hp + (size_t)s0 * FEAT);
        fma_pair(al0.x, h0.x, acc[0], acc[1]);
        fma_pair(al0.y, h0.y, acc[2], acc[3]);
        fma_pair(al0.z, h0.z, acc[4], acc[5]);
        fma_pair(al0.w, h0.w, acc[6], acc[7]);
    }
#pragma unroll
    for (int h = 0; h < NHEADS; ++h) {
        int c = h * DHEAD + t;
        out[(size_t)n * FEAT + c] = acc[h] + bias[c];
    }
}

extern "C" void kernel_launch(void* const* d_in, const int* in_sizes, int n_in,
                              void* d_out, int out_size, void* d_ws, size_t ws_size,
                              hipStream_t stream) {
    const float* x = (const float*)d_in[0];
    const int* n_id = (const int*)d_in[1];
    const float* attns = (const float*)d_in[2];
    const int* edges = (const int*)d_in[3];
    const float* nw = (const float*)d_in[4];
    const float* W = (const float*)d_in[5];
    const float* bias = (const float*)d_in[6];
    float* out = (float*)d_out;

    char* ws = (char*)d_ws;
    size_t o = 0;
    ushort_t* hfeatq = (ushort_t*)(ws + o); o += 10240000;   // [N][D][H] bf16
    ushort_t* alphab = (ushort_t*)(ws + o); o += 7680000;    // [Etot][H] bf16, dst-sorted
    ushort_t* xb     = (ushort_t*)(ws + o); o += 10240000;
    ushort_t* wbt    = (ushort_t*)(ws + o); o += 524288;
    int* src_sorted  = (int*)(ws + o);      o += 1920000;
    int* counts      = (int*)(ws + o);      o += 40000;
    int* cursor      = (int*)(ws + o);      o += 40000;
    int* offsets     = (int*)(ws + o);      o += 40016;
    int* inv         = (int*)(ws + o);      o += 40000;
    // total ~30.8 MB

    hipMemsetAsync(counts, 0, 80000, stream);  // counts + cursor (adjacent)
    build_inv_kernel<<<(NNODES + 255) / 256, 256, 0, stream>>>(n_id, inv);
    hist_kernel<<<(ETOT + 255) / 256, 256, 0, stream>>>(edges, inv, counts);
    scan_kernel<<<1, 1024, 0, stream>>>(counts, offsets);
    scatter_kernel<<<(ETOT + 255) / 256, 256, 0, stream>>>(edges, inv, offsets, cursor,
                                                           attns, nw, src_sorted, alphab);
    cvt_x_kernel<<<(NNODES * FEAT / 4 + 255) / 256, 256, 0, stream>>>(x, xb);
    dim3 wgrid(FEAT / 32, FEAT / 32);
    cvt_wt_kernel<<<wgrid, 256, 0, stream>>>(W, wbt);
    dim3 ggrid(FEAT / 128, (NNODES + 127) / 128);
    gemm_mfma_kernel<<<ggrid, 256, 0, stream>>>(xb, wbt, hfeatq);
    aggregate_kernel<<<(NNODES + 3) / 4, 256, 0, stream>>>(src_sorted, offsets, alphab,
                                                           hfeatq, bias, out);
}